// Round 3
// baseline (406.434 us; speedup 1.0000x reference)
//
#include <hip/hip_runtime.h>
#include <math.h>

#define KS    31
#define PADV  15
#define IMG   320
#define NOUT  289                  // valid centered outputs (i in [15, 304))
#define NPIX  (NOUT * NOUT)        // 83521 inner pixels
#define NTH   180
#define NFR   20
#define NKER  (NTH * NFR)          // 3600 distinct kernels

// workspace byte offsets
#define OFF_MM     0
#define OFF_HIST   256
#define OFF_CURS   (OFF_HIST + NKER * 4)
#define OFF_OFFS   (OFF_CURS + NKER * 4)
#define OFF_PLIST  (OFF_OFFS + (NKER + 4) * 4)
#define WS_NEED    (OFF_PLIST + NPIX * 4)

__device__ __forceinline__ unsigned int ordkey(float f) {
    unsigned int b = __float_as_uint(f);
    return (b & 0x80000000u) ? ~b : (b | 0x80000000u);
}
__device__ __forceinline__ float ordval(unsigned int k) {
    unsigned int b = (k & 0x80000000u) ? (k & 0x7FFFFFFFu) : ~k;
    return __uint_as_float(b);
}

// ---- init: reset min/max and zero histogram ----
__global__ __launch_bounds__(256) void init_ws(unsigned int* mm, int* hist) {
    int i = blockIdx.x * 256 + threadIdx.x;
    if (i == 0) { mm[0] = 0xFFFFFFFFu; mm[1] = 0u; }
    if (i < NKER) hist[i] = 0;
}

// ---- pass 1: histogram of kernel indices over inner pixels ----
__global__ __launch_bounds__(256) void hist_kernel(
    const int* __restrict__ fmap, const int* __restrict__ tmap,
    int* __restrict__ hist)
{
    int p = blockIdx.x * 256 + threadIdx.x;
    if (p >= NPIX) return;
    int oy = p / NOUT, ox = p - oy * NOUT;
    int pix = (oy + PADV) * IMG + (ox + PADV);
    int kidx = tmap[pix] * NFR + fmap[pix];
    atomicAdd(&hist[kidx], 1);
}

// ---- pass 2: exclusive prefix scan over 3600 bins (single block) ----
__global__ __launch_bounds__(256) void scan_kernel(
    const int* __restrict__ hist, int* __restrict__ offsets,
    int* __restrict__ cursor)
{
    __shared__ int part[256];
    const int tid = threadIdx.x;
    const int CH = (NKER + 255) / 256;     // 15
    int b0 = tid * CH;
    int s = 0;
    for (int i = 0; i < CH; ++i) { int b = b0 + i; if (b < NKER) s += hist[b]; }
    part[tid] = s;
    __syncthreads();
    for (int off = 1; off < 256; off <<= 1) {
        int v = (tid >= off) ? part[tid - off] : 0;
        __syncthreads();
        part[tid] += v;
        __syncthreads();
    }
    int run = part[tid] - s;               // exclusive prefix of this chunk
    for (int i = 0; i < CH; ++i) {
        int b = b0 + i;
        if (b < NKER) { offsets[b] = run; cursor[b] = run; run += hist[b]; }
    }
    if (tid == 255) offsets[NKER] = part[255];
}

// ---- pass 3: scatter pixel ids into per-kidx lists ----
__global__ __launch_bounds__(256) void scatter_kernel(
    const int* __restrict__ fmap, const int* __restrict__ tmap,
    int* __restrict__ cursor, int* __restrict__ plist)
{
    int p = blockIdx.x * 256 + threadIdx.x;
    if (p >= NPIX) return;
    int oy = p / NOUT, ox = p - oy * NOUT;
    int pix = (oy + PADV) * IMG + (ox + PADV);
    int kidx = tmap[pix] * NFR + fmap[pix];
    int pos = atomicAdd(&cursor[kidx], 1);
    plist[pos] = pix;                      // store out-index directly
}

// ---- conv: one block per kidx; kernel built in LDS; wave per pixel ----
__global__ __launch_bounds__(256) void conv_sorted(
    const float* __restrict__ fp, const int* __restrict__ offsets,
    const int* __restrict__ plist, float* __restrict__ out,
    unsigned int* __restrict__ mm)
{
    __shared__ float kl[32 * 32];
    const int b = blockIdx.x;
    const int tid = threadIdx.x;
    const int t = b / NFR, f = b - t * NFR;

    // build this (theta,freq) Gabor kernel in LDS, zero-padded to 32x32
    {
        const float th = ((float)t / 180.0f) * 3.14159265358979323846f;
        const float f0 = 0.025f + 0.0015f * (float)f;
        float st, ct;
        sincosf(th, &st, &ct);
        const float fch = f0 * (1.0f / 45.0f);
        const float TWO_PI = 6.28318530717958647692f;
        #pragma unroll
        for (int g = 0; g < 4; ++g) {
            int e = g * 256 + tid;
            int dy = e >> 5, dx = e & 31;
            float val = 0.0f;
            if (dy < KS && dx < KS) {
                float y = (float)(dy - PADV);
                float x = (float)(dx - PADV);
                float x_t = fmaf(x,  ct, y * st);
                float y_t = fmaf(-x, st, y * ct);
                float f_local = fmaf(fch, y_t, f0);
                float gamma   = fmaf(0.04f, fabsf(y_t), 1.0f);
                float gyt = gamma * y_t;
                float env = expf(-(x_t * x_t + gyt * gyt) * (1.0f / 72.0f));
                val = env * cosf(TWO_PI * f_local * x_t);
            }
            kl[e] = val;
        }
    }
    __syncthreads();

    const int start = offsets[b], end = offsets[b + 1];
    const int wave = tid >> 6, lane = tid & 63;
    const int laneoff = (lane >> 5) * IMG + (lane & 31);  // row0/col within window
    float vmin = INFINITY, vmax = -INFINITY;

    for (int idx = start + wave; idx < end; idx += 4) {
        const int p = plist[idx];                          // iy*IMG+ix
        const float* base = fp + (p - (PADV * IMG + PADV)) + laneoff;
        float acc = 0.0f;
        #pragma unroll
        for (int g = 0; g < 16; ++g) {
            acc = fmaf(base[g * (2 * IMG)], kl[g * 64 + lane], acc);
        }
        for (int off = 32; off; off >>= 1) acc += __shfl_down(acc, off, 64);
        if (lane == 0) {
            out[p] = acc;
            vmin = fminf(vmin, acc);
            vmax = fmaxf(vmax, acc);
        }
    }
    if (lane == 0 && vmax >= vmin) {       // had at least one pixel
        atomicMin(&mm[0], ordkey(vmin));
        atomicMax(&mm[1], ordkey(vmax));
    }
}

// ---- Fallback (round-1 kernel) if ws is too small ----
#define FTILE 16
#define FLT   (FTILE + KS - 1)
__global__ __launch_bounds__(256) void gabor_main(
    const float* __restrict__ fp, const int* __restrict__ fmap,
    const int* __restrict__ tmap, float* __restrict__ out,
    unsigned int* __restrict__ mm)
{
    __shared__ float tile[FLT * FLT];
    const int bh = blockIdx.y * FTILE;
    const int bw = blockIdx.x * FTILE;
    const int tid = threadIdx.x;
    for (int i = tid; i < FLT * FLT; i += 256) {
        int r = i / FLT, c = i - r * FLT;
        int gr = bh + r, gc = bw + c;
        tile[i] = (gr < IMG && gc < IMG) ? fp[gr * IMG + gc] : 0.0f;
    }
    __syncthreads();
    const int tx = tid & (FTILE - 1), ty = tid >> 4;
    const int oy = bh + ty, ox = bw + tx;
    float vmin = INFINITY, vmax = -INFINITY;
    if (oy < NOUT && ox < NOUT) {
        const int iy = oy + PADV, ix = ox + PADV;
        float th = ((float)tmap[iy * IMG + ix] / 180.0f) * 3.14159265358979323846f;
        float f0 = 0.025f + 0.0015f * (float)fmap[iy * IMG + ix];
        float st, ct;
        sincosf(th, &st, &ct);
        const float fch = f0 * (1.0f / 45.0f);
        const float TWO_PI = 6.28318530717958647692f;
        float acc = 0.0f;
        for (int dy = 0; dy < KS; ++dy) {
            const float y = (float)(dy - PADV);
            const float yct = y * ct, yst = y * st;
            const float* trow = &tile[(ty + dy) * FLT + tx];
            for (int dx = 0; dx < KS; ++dx) {
                float x = (float)(dx - PADV);
                float x_t = fmaf(x,  ct, yst);
                float y_t = fmaf(-x, st, yct);
                float f_local = fmaf(fch, y_t, f0);
                float gamma   = fmaf(0.04f, fabsf(y_t), 1.0f);
                float gyt = gamma * y_t;
                float e = expf(-(x_t * x_t + gyt * gyt) * (1.0f / 72.0f));
                float c = cosf(TWO_PI * f_local * x_t);
                acc = fmaf(trow[dx], e * c, acc);
            }
        }
        out[iy * IMG + ix] = acc;
        vmin = acc; vmax = acc;
    }
    for (int off = 32; off; off >>= 1) {
        vmin = fminf(vmin, __shfl_down(vmin, off, 64));
        vmax = fmaxf(vmax, __shfl_down(vmax, off, 64));
    }
    if ((tid & 63) == 0) {
        atomicMin(&mm[0], ordkey(vmin));
        atomicMax(&mm[1], ordkey(vmax));
    }
}

__global__ __launch_bounds__(256) void border_copy(
    const float* __restrict__ fp, float* __restrict__ out,
    unsigned int* __restrict__ mm)
{
    int p = blockIdx.x * 256 + threadIdx.x;
    float vmin = INFINITY, vmax = -INFINITY;
    if (p < IMG * IMG) {
        int i = p / IMG, j = p - i * IMG;
        bool inner = (i >= PADV) && (i < PADV + NOUT) && (j >= PADV) && (j < PADV + NOUT);
        if (!inner) {
            float v = fp[p];
            out[p] = v;
            vmin = v; vmax = v;
        }
    }
    for (int off = 32; off; off >>= 1) {
        vmin = fminf(vmin, __shfl_down(vmin, off, 64));
        vmax = fmaxf(vmax, __shfl_down(vmax, off, 64));
    }
    if ((threadIdx.x & 63) == 0) {
        atomicMin(&mm[0], ordkey(vmin));
        atomicMax(&mm[1], ordkey(vmax));
    }
}

__global__ __launch_bounds__(256) void finalize(
    float* __restrict__ out, const unsigned int* __restrict__ mm)
{
    int p = blockIdx.x * 256 + threadIdx.x;
    if (p >= IMG * IMG) return;
    float mn = ordval(mm[0]);
    float mx = ordval(mm[1]) - mn;
    float v  = out[p] - mn;
    if (mx != 0.0f) v = v / mx * 100.0f;
    out[p] = (v > 55.0f) ? 100.0f : 0.0f;
}

extern "C" void kernel_launch(void* const* d_in, const int* in_sizes, int n_in,
                              void* d_out, int out_size, void* d_ws, size_t ws_size,
                              hipStream_t stream) {
    const float* fp   = (const float*)d_in[0];
    const int*   fmap = (const int*)d_in[1];
    const int*   tmap = (const int*)d_in[2];
    float* out = (float*)d_out;

    char* ws = (char*)d_ws;
    unsigned int* mm   = (unsigned int*)(ws + OFF_MM);
    int* hist    = (int*)(ws + OFF_HIST);
    int* cursor  = (int*)(ws + OFF_CURS);
    int* offsets = (int*)(ws + OFF_OFFS);
    int* plist   = (int*)(ws + OFF_PLIST);

    const int nblk_img = (IMG * IMG + 255) / 256;
    const int nblk_pix = (NPIX + 255) / 256;

    if (ws_size >= (size_t)WS_NEED) {
        hipLaunchKernelGGL(init_ws, dim3((NKER + 255) / 256), dim3(256), 0, stream, mm, hist);
        hipLaunchKernelGGL(hist_kernel, dim3(nblk_pix), dim3(256), 0, stream, fmap, tmap, hist);
        hipLaunchKernelGGL(scan_kernel, dim3(1), dim3(256), 0, stream, hist, offsets, cursor);
        hipLaunchKernelGGL(scatter_kernel, dim3(nblk_pix), dim3(256), 0, stream, fmap, tmap, cursor, plist);
        hipLaunchKernelGGL(conv_sorted, dim3(NKER), dim3(256), 0, stream, fp, offsets, plist, out, mm);
    } else {
        hipLaunchKernelGGL(init_ws, dim3((NKER + 255) / 256), dim3(256), 0, stream, mm, hist);
        dim3 g((NOUT + FTILE - 1) / FTILE, (NOUT + FTILE - 1) / FTILE);
        hipLaunchKernelGGL(gabor_main, g, dim3(256), 0, stream, fp, fmap, tmap, out, mm);
    }

    hipLaunchKernelGGL(border_copy, dim3(nblk_img), dim3(256), 0, stream, fp, out, mm);
    hipLaunchKernelGGL(finalize,    dim3(nblk_img), dim3(256), 0, stream, out, mm);
}

// Round 4
// 189.739 us; speedup vs baseline: 2.1421x; 2.1421x over previous
//
#include <hip/hip_runtime.h>
#include <math.h>

#define KS    31
#define PADV  15
#define IMG   320
#define NOUT  289          // valid centered outputs (i in [15, 304))
#define TB    8            // 8x8 output pixels per block
#define TROWS 38           // TB + KS - 1
#define TSTR  39           // padded LDS row stride (odd -> conflict-free)

__device__ __forceinline__ unsigned int ordkey(float f) {
    unsigned int b = __float_as_uint(f);
    return (b & 0x80000000u) ? ~b : (b | 0x80000000u);
}
__device__ __forceinline__ float ordval(unsigned int k) {
    unsigned int b = (k & 0x80000000u) ? (k & 0x7FFFFFFFu) : ~k;
    return __uint_as_float(b);
}

__global__ void init_mm(unsigned int* mm) {
    mm[0] = 0xFFFFFFFFu;   // running-min key
    mm[1] = 0u;            // running-max key
}

// 256 threads = 64 pixels x 4 row-parts. Part q handles kernel rows q*8..q*8+7.
__global__ __launch_bounds__(256) void gabor_fast(
    const float* __restrict__ fp, const int* __restrict__ fmap,
    const int* __restrict__ tmap, float* __restrict__ out,
    unsigned int* __restrict__ mm)
{
    __shared__ float tile[TROWS * TSTR];
    const int bh = blockIdx.y * TB;
    const int bw = blockIdx.x * TB;
    const int tid = threadIdx.x;

    // stage 38x38 image window (stride 39, pad col zero-filled implicitly unread)
    for (int i = tid; i < TROWS * TSTR; i += 256) {
        int r = i / TSTR, c = i - r * TSTR;
        int gr = bh + r, gc = bw + c;
        tile[i] = (gr < IMG && gc < IMG) ? fp[gr * IMG + gc] : 0.0f;
    }
    __syncthreads();

    const int pixel = tid >> 2, part = tid & 3;   // parts of a pixel: adjacent lanes
    const int px = pixel & 7, py = pixel >> 3;
    const int oy = bh + py, ox = bw + px;
    const bool valid = (oy < NOUT) && (ox < NOUT);

    float acc0 = 0.0f, acc1 = 0.0f;
    if (valid) {
        const int iy = oy + PADV, ix = ox + PADV;
        const float th = ((float)tmap[iy * IMG + ix] / 180.0f) * 3.14159265358979323846f;
        const float f0 = 0.025f + 0.0015f * (float)fmap[iy * IMG + ix];
        float st, ct;
        sincosf(th, &st, &ct);
        const float fch = f0 * (1.0f / 45.0f);       // (f0/3)/half
        const float TWO_PI = 6.28318530717958647692f;

        #pragma unroll
        for (int r = 0; r < 8; ++r) {
            const int dy = part * 8 + r;
            if (dy > 30) break;                       // part 3 has 7 rows
            const float y   = (float)(dy - PADV);
            const float yct = y * ct, yst = y * st;
            const float* trow = &tile[(py + dy) * TSTR + px];
            #pragma unroll
            for (int c = 0; c < KS; ++c) {
                float x   = (float)(c - PADV);
                float x_t = fmaf(x,  ct, yst);
                float y_t = fmaf(-x, st, yct);
                float g   = fmaf(0.04f, fabsf(y_t), 1.0f);   // 1 + 0.6*|y_t|/15
                float gyt = g * y_t;
                float s2  = fmaf(x_t, x_t, gyt * gyt);
                float e   = __expf(s2 * (-1.0f / 72.0f));
                float fl  = fmaf(fch, y_t, f0);
                float cc  = __cosf(TWO_PI * fl * x_t);
                float w   = e * cc;
                if (c & 1) acc1 = fmaf(trow[c], w, acc1);
                else       acc0 = fmaf(trow[c], w, acc0);
            }
        }
    }

    // combine the 4 row-parts (adjacent lanes) of each pixel
    float v = acc0 + acc1;
    v += __shfl_xor(v, 1, 64);
    v += __shfl_xor(v, 2, 64);

    float vmin = INFINITY, vmax = -INFINITY;
    if (valid && part == 0) {
        out[(oy + PADV) * IMG + (ox + PADV)] = v;
        vmin = v; vmax = v;
    }
    for (int off = 32; off; off >>= 1) {
        vmin = fminf(vmin, __shfl_down(vmin, off, 64));
        vmax = fmaxf(vmax, __shfl_down(vmax, off, 64));
    }
    if ((tid & 63) == 0) {
        atomicMin(&mm[0], ordkey(vmin));
        atomicMax(&mm[1], ordkey(vmax));
    }
}

__global__ __launch_bounds__(256) void border_copy(
    const float* __restrict__ fp, float* __restrict__ out,
    unsigned int* __restrict__ mm)
{
    int p = blockIdx.x * 256 + threadIdx.x;
    float vmin = INFINITY, vmax = -INFINITY;
    if (p < IMG * IMG) {
        int i = p / IMG, j = p - i * IMG;
        bool inner = (i >= PADV) && (i < PADV + NOUT) && (j >= PADV) && (j < PADV + NOUT);
        if (!inner) {
            float v = fp[p];
            out[p] = v;
            vmin = v; vmax = v;
        }
    }
    for (int off = 32; off; off >>= 1) {
        vmin = fminf(vmin, __shfl_down(vmin, off, 64));
        vmax = fmaxf(vmax, __shfl_down(vmax, off, 64));
    }
    if ((threadIdx.x & 63) == 0) {
        atomicMin(&mm[0], ordkey(vmin));
        atomicMax(&mm[1], ordkey(vmax));
    }
}

__global__ __launch_bounds__(256) void finalize(
    float* __restrict__ out, const unsigned int* __restrict__ mm)
{
    int p = blockIdx.x * 256 + threadIdx.x;
    if (p >= IMG * IMG) return;
    float mn = ordval(mm[0]);
    float mx = ordval(mm[1]) - mn;       // max(out - min) == max0 - min0
    float v  = out[p] - mn;
    if (mx != 0.0f) v = v / mx * 100.0f;
    out[p] = (v > 55.0f) ? 100.0f : 0.0f;
}

extern "C" void kernel_launch(void* const* d_in, const int* in_sizes, int n_in,
                              void* d_out, int out_size, void* d_ws, size_t ws_size,
                              hipStream_t stream) {
    const float* fp   = (const float*)d_in[0];
    const int*   fmap = (const int*)d_in[1];
    const int*   tmap = (const int*)d_in[2];
    float* out = (float*)d_out;
    unsigned int* mm = (unsigned int*)d_ws;

    hipLaunchKernelGGL(init_mm, dim3(1), dim3(1), 0, stream, mm);

    dim3 g((NOUT + TB - 1) / TB, (NOUT + TB - 1) / TB);   // 37 x 37
    hipLaunchKernelGGL(gabor_fast, g, dim3(256), 0, stream, fp, fmap, tmap, out, mm);

    int nblk = (IMG * IMG + 255) / 256;
    hipLaunchKernelGGL(border_copy, dim3(nblk), dim3(256), 0, stream, fp, out, mm);
    hipLaunchKernelGGL(finalize,    dim3(nblk), dim3(256), 0, stream, out, mm);
}